// Round 3
// baseline (215.884 us; speedup 1.0000x reference)
//
#include <hip/hip_runtime.h>
#include <math.h>

#define IMGF 640.0f
#define EPSF 1e-7f
#define NBOX 60
#define NCLS 80
#define NB   64
#define NTH  512
#define NBLK (3 * NB)
#define PIF  3.14159265358979323846f

__device__ __forceinline__ float bce_fast(float x, float t) {
    return fmaxf(x, 0.0f) - x * t + __logf(1.0f + __expf(-fabsf(x)));
}
__device__ __forceinline__ float bce0_fast(float x) {
    return fmaxf(x, 0.0f) + __logf(1.0f + __expf(-fabsf(x)));
}
__device__ __forceinline__ float sigmoidf_(float x) {
    return 1.0f / (1.0f + __expf(-x));
}
__device__ __forceinline__ float wave_reduce(float v) {
    #pragma unroll
    for (int o = 32; o > 0; o >>= 1) v += __shfl_down(v, o, 64);
    return v;
}

// ws layout: ws[0..3] = float accumulators (box, obj, cls, npos), ws[4] = uint ticket
__global__ __launch_bounds__(NTH) void detloss_fused(
    const float* __restrict__ p3b, const float* __restrict__ p3o, const float* __restrict__ p3c,
    const float* __restrict__ p4b, const float* __restrict__ p4o, const float* __restrict__ p4c,
    const float* __restrict__ p5b, const float* __restrict__ p5o, const float* __restrict__ p5c,
    const float* __restrict__ boxes, const int* __restrict__ labels,
    float* __restrict__ ws, float* __restrict__ out)
{
    const int bid = blockIdx.x;
    const int s = bid / NB;      // scale 0,1,2
    const int b = bid % NB;      // image
    const int tid = threadIdx.x;

    const float* reg; const float* obj; const float* cls;
    int H; float stridef, mn, mx;
    if (s == 0)      { reg = p3b; obj = p3o; cls = p3c; H = 80; stridef = 8.0f;  mn = 0.0f;   mx = 64.0f; }
    else if (s == 1) { reg = p4b; obj = p4o; cls = p4c; H = 40; stridef = 16.0f; mn = 64.0f;  mx = 128.0f; }
    else             { reg = p5b; obj = p5o; cls = p5c; H = 20; stridef = 32.0f; mn = 128.0f; mx = 10000.0f; }
    const int W = H, HW = H * W;
    reg += (size_t)b * 4 * HW;
    obj += (size_t)b * HW;
    cls += (size_t)b * NCLS * HW;
    const float sf = stridef / IMGF;

    __shared__ int sh_cell[NBOX];
    __shared__ int sh_lab[NBOX];
    __shared__ int sh_mask[NBOX];
    __shared__ float red[6 * 8];

    float box_p = 0.0f, objp_p = 0.0f, cls_p = 0.0f;
    float neg_p = 0.0f, sub_p = 0.0f, npos_p = 0.0f;

    // Phase A: per-box mask, cell, CIoU, obj-pos (wave 0 only; waves 1..7
    // proceed straight to Phase D and overlap these scattered gathers)
    if (tid < NBOX) {
        const size_t bb = ((size_t)b * NBOX + tid) * 4;
        const float bcx = boxes[bb + 0];
        const float bcy = boxes[bb + 1];
        const float bw  = boxes[bb + 2];
        const float bh  = boxes[bb + 3];
        const float tmax = fmaxf(bw, bh) * IMGF;
        const int m = (tmax > mn) && (tmax <= mx);
        int cx = (int)(bcx * (float)W); cx = min(max(cx, 0), W - 1);
        int cy = (int)(bcy * (float)H); cy = min(max(cy, 0), H - 1);
        const int cell = cy * W + cx;
        sh_cell[tid] = cell;
        sh_lab[tid]  = labels[b * NBOX + tid];
        sh_mask[tid] = m;
        if (m) {
            npos_p = 1.0f;
            const float tx = sigmoidf_(reg[0 * HW + cell]);
            const float ty = sigmoidf_(reg[1 * HW + cell]);
            const float tw = __expf(reg[2 * HW + cell]);
            const float th = __expf(reg[3 * HW + cell]);
            const float pcx = ((float)cx + tx) * sf;
            const float pcy = ((float)cy + ty) * sf;
            const float pw = tw * sf, ph = th * sf;
            const float px1 = pcx - pw * 0.5f, px2 = pcx + pw * 0.5f;
            const float py1 = pcy - ph * 0.5f, py2 = pcy + ph * 0.5f;
            const float qx1 = bcx - bw * 0.5f, qx2 = bcx + bw * 0.5f;
            const float qy1 = bcy - bh * 0.5f, qy2 = bcy + bh * 0.5f;
            const float iw = fmaxf(fminf(px2, qx2) - fmaxf(px1, qx1), 0.0f);
            const float ih = fmaxf(fminf(py2, qy2) - fmaxf(py1, qy1), 0.0f);
            const float inter = iw * ih;
            const float uni = (px2 - px1) * (py2 - py1) + (qx2 - qx1) * (qy2 - qy1) - inter;
            const float iou = inter / (uni + EPSF);
            const float cw = fmaxf(px2, qx2) - fminf(px1, qx1);
            const float ch = fmaxf(py2, qy2) - fminf(py1, qy1);
            const float c2 = cw * cw + ch * ch + EPSF;
            const float dx = qx1 + qx2 - px1 - px2;
            const float dy = qy1 + qy2 - py1 - py2;
            const float rho2 = (dx * dx + dy * dy) * 0.25f;
            const float wp = px2 - px1, hp = py2 - py1;
            const float wg = qx2 - qx1, hg = qy2 - qy1;
            const float da = atanf(wg / (hg + EPSF)) - atanf(wp / (hp + EPSF));
            const float v = (4.0f / (PIF * PIF)) * da * da;
            const float alpha = v / (1.0f - iou + v + EPSF);
            float ci = iou - rho2 / c2 - alpha * v;
            ci = fminf(fmaxf(ci, -1.0f), 1.0f);
            box_p  = 1.0f - ci;
            objp_p = bce_fast(obj[cell], 1.0f);
        }
    }

    // Phase D: full-map negative objectness sum (no LDS dependency; float4)
    {
        const float4* obj4 = (const float4*)obj;
        const int n4 = HW >> 2;
        for (int i = tid; i < n4; i += NTH) {
            const float4 v = obj4[i];
            neg_p += bce0_fast(v.x) + bce0_fast(v.y) + bce0_fast(v.z) + bce0_fast(v.w);
        }
    }
    __syncthreads();

    // Phase B: subtract bce(obj,0) once per DISTINCT positive cell
    if (tid < NBOX && sh_mask[tid]) {
        const int cell = sh_cell[tid];
        bool first = true;
        for (int j = 0; j < tid; ++j)
            if (sh_mask[j] && sh_cell[j] == cell) { first = false; break; }
        if (first) sub_p = bce0_fast(obj[cell]);
    }

    // Phase C: class BCE, fully unrolled so all ~10 scattered loads are in
    // flight simultaneously (one ~900-cyc latency round instead of five)
    {
        float xs[10], tg[10];
        bool  act[10];
        #pragma unroll
        for (int k = 0; k < 10; ++k) {
            const int i = tid + k * NTH;
            act[k] = false;
            if (i < NBOX * NCLS) {
                const int n = i / NCLS;
                const int c = i - n * NCLS;
                if (sh_mask[n]) {
                    act[k] = true;
                    xs[k]  = cls[(size_t)c * HW + sh_cell[n]];
                    tg[k]  = (c == sh_lab[n]) ? 1.0f : 0.0f;
                }
            }
        }
        #pragma unroll
        for (int k = 0; k < 10; ++k)
            if (act[k]) cls_p += bce_fast(xs[k], tg[k]);
    }

    // Block reduction of 6 partials
    float vals[6] = { box_p, objp_p, cls_p, neg_p, sub_p, npos_p };
    const int wave = tid >> 6, lane = tid & 63;
    #pragma unroll
    for (int k = 0; k < 6; ++k) {
        const float v = wave_reduce(vals[k]);
        if (lane == 0) red[k * 8 + wave] = v;
    }
    __syncthreads();

    if (tid == 0) {
        float t[6];
        #pragma unroll
        for (int k = 0; k < 6; ++k) {
            float acc = 0.0f;
            #pragma unroll
            for (int w = 0; w < 8; ++w) acc += red[k * 8 + w];
            t[k] = acc;
        }
        const bool has_pos = t[5] > 0.0f;
        const float obj_l = has_pos ? (t[1] + (t[3] - t[4]) * 0.05f)
                                    : (t[3] / (float)HW) * 0.1f;
        // Device-scope accumulate (ws[0..4] zeroed by the memset node)
        atomicAdd(&ws[0], has_pos ? t[0] : 0.0f);
        atomicAdd(&ws[1], obj_l);
        atomicAdd(&ws[2], has_pos ? t[2] : 0.0f);
        atomicAdd(&ws[3], t[5]);
        __threadfence();
        unsigned* ticket = (unsigned*)&ws[4];
        const unsigned old = atomicAdd(ticket, 1u);
        if (old == NBLK - 1) {
            // Last block: all prior adds are globally visible (each preceded
            // its ticket increment with a __threadfence). Read via atomics to
            // bypass any stale L1 line.
            const float tb = atomicAdd(&ws[0], 0.0f);
            const float to = atomicAdd(&ws[1], 0.0f);
            const float tc = atomicAdd(&ws[2], 0.0f);
            const float tn = atomicAdd(&ws[3], 0.0f);
            const float norm = fmaxf(tn, 1.0f);
            const float box_loss = tb / norm;
            const float cls_loss = tc / norm;
            const float obj_loss = to / (float)(NB * 3);
            out[0] = 7.5f * box_loss + obj_loss + 0.5f * cls_loss;
            out[1] = box_loss;
            out[2] = obj_loss;
            out[3] = cls_loss;
        }
    }
}

extern "C" void kernel_launch(void* const* d_in, const int* in_sizes, int n_in,
                              void* d_out, int out_size, void* d_ws, size_t ws_size,
                              hipStream_t stream) {
    const float* p3b = (const float*)d_in[0];
    const float* p3o = (const float*)d_in[1];
    const float* p3c = (const float*)d_in[2];
    const float* p4b = (const float*)d_in[3];
    const float* p4o = (const float*)d_in[4];
    const float* p4c = (const float*)d_in[5];
    const float* p5b = (const float*)d_in[6];
    const float* p5o = (const float*)d_in[7];
    const float* p5c = (const float*)d_in[8];
    const float* boxes = (const float*)d_in[9];
    const int*   labels = (const int*)d_in[10];

    // Zero the 5-word accumulator block (graph-capturable memset node)
    hipMemsetAsync(d_ws, 0, 32, stream);

    detloss_fused<<<dim3(NBLK), dim3(NTH), 0, stream>>>(
        p3b, p3o, p3c, p4b, p4o, p4c, p5b, p5o, p5c, boxes, labels,
        (float*)d_ws, (float*)d_out);
}

// Round 4
// 205.545 us; speedup vs baseline: 1.0503x; 1.0503x over previous
//
#include <hip/hip_runtime.h>
#include <math.h>

#define IMGF 640.0f
#define EPSF 1e-7f
#define NBOX 60
#define NCLS 80
#define NB   64
#define NTH  512
#define PIF  3.14159265358979323846f

__device__ __forceinline__ float bce_fast(float x, float t) {
    return fmaxf(x, 0.0f) - x * t + __logf(1.0f + __expf(-fabsf(x)));
}
__device__ __forceinline__ float bce0_fast(float x) {
    return fmaxf(x, 0.0f) + __logf(1.0f + __expf(-fabsf(x)));
}
__device__ __forceinline__ float sigmoidf_(float x) {
    return 1.0f / (1.0f + __expf(-x));
}
__device__ __forceinline__ float wave_reduce(float v) {
    #pragma unroll
    for (int o = 32; o > 0; o >>= 1) v += __shfl_down(v, o, 64);
    return v;
}

// One block per (scale, image). Writes [box_l, obj_l, cls_l, npos] per block.
__global__ __launch_bounds__(NTH) void detloss_main(
    const float* __restrict__ p3b, const float* __restrict__ p3o, const float* __restrict__ p3c,
    const float* __restrict__ p4b, const float* __restrict__ p4o, const float* __restrict__ p4c,
    const float* __restrict__ p5b, const float* __restrict__ p5o, const float* __restrict__ p5c,
    const float* __restrict__ boxes, const int* __restrict__ labels,
    float* __restrict__ part)
{
    const int bid = blockIdx.x;
    const int s = bid / NB;      // scale 0,1,2
    const int b = bid % NB;      // image
    const int tid = threadIdx.x;

    const float* reg; const float* obj; const float* cls;
    int H; float stridef, mn, mx;
    if (s == 0)      { reg = p3b; obj = p3o; cls = p3c; H = 80; stridef = 8.0f;  mn = 0.0f;   mx = 64.0f; }
    else if (s == 1) { reg = p4b; obj = p4o; cls = p4c; H = 40; stridef = 16.0f; mn = 64.0f;  mx = 128.0f; }
    else             { reg = p5b; obj = p5o; cls = p5c; H = 20; stridef = 32.0f; mn = 128.0f; mx = 10000.0f; }
    const int W = H, HW = H * W;
    reg += (size_t)b * 4 * HW;
    obj += (size_t)b * HW;
    cls += (size_t)b * NCLS * HW;
    const float sf = stridef / IMGF;

    __shared__ int sh_cell[NBOX];
    __shared__ int sh_lab[NBOX];
    __shared__ int sh_mask[NBOX];
    __shared__ float red[6 * 8];

    float box_p = 0.0f, objp_p = 0.0f, cls_p = 0.0f;
    float neg_p = 0.0f, sub_p = 0.0f, npos_p = 0.0f;

    // Phase A: per-box mask, cell, CIoU, obj-pos (wave 0 only; waves 1..7
    // proceed straight to Phase D and overlap these scattered gathers)
    if (tid < NBOX) {
        const size_t bb = ((size_t)b * NBOX + tid) * 4;
        const float bcx = boxes[bb + 0];
        const float bcy = boxes[bb + 1];
        const float bw  = boxes[bb + 2];
        const float bh  = boxes[bb + 3];
        const float tmax = fmaxf(bw, bh) * IMGF;
        const int m = (tmax > mn) && (tmax <= mx);
        int cx = (int)(bcx * (float)W); cx = min(max(cx, 0), W - 1);
        int cy = (int)(bcy * (float)H); cy = min(max(cy, 0), H - 1);
        const int cell = cy * W + cx;
        sh_cell[tid] = cell;
        sh_lab[tid]  = labels[b * NBOX + tid];
        sh_mask[tid] = m;
        if (m) {
            npos_p = 1.0f;
            const float tx = sigmoidf_(reg[0 * HW + cell]);
            const float ty = sigmoidf_(reg[1 * HW + cell]);
            const float tw = __expf(reg[2 * HW + cell]);
            const float th = __expf(reg[3 * HW + cell]);
            const float pcx = ((float)cx + tx) * sf;
            const float pcy = ((float)cy + ty) * sf;
            const float pw = tw * sf, ph = th * sf;
            const float px1 = pcx - pw * 0.5f, px2 = pcx + pw * 0.5f;
            const float py1 = pcy - ph * 0.5f, py2 = pcy + ph * 0.5f;
            const float qx1 = bcx - bw * 0.5f, qx2 = bcx + bw * 0.5f;
            const float qy1 = bcy - bh * 0.5f, qy2 = bcy + bh * 0.5f;
            const float iw = fmaxf(fminf(px2, qx2) - fmaxf(px1, qx1), 0.0f);
            const float ih = fmaxf(fminf(py2, qy2) - fmaxf(py1, qy1), 0.0f);
            const float inter = iw * ih;
            const float uni = (px2 - px1) * (py2 - py1) + (qx2 - qx1) * (qy2 - qy1) - inter;
            const float iou = inter / (uni + EPSF);
            const float cw = fmaxf(px2, qx2) - fminf(px1, qx1);
            const float ch = fmaxf(py2, qy2) - fminf(py1, qy1);
            const float c2 = cw * cw + ch * ch + EPSF;
            const float dx = qx1 + qx2 - px1 - px2;
            const float dy = qy1 + qy2 - py1 - py2;
            const float rho2 = (dx * dx + dy * dy) * 0.25f;
            const float wp = px2 - px1, hp = py2 - py1;
            const float wg = qx2 - qx1, hg = qy2 - qy1;
            const float da = atanf(wg / (hg + EPSF)) - atanf(wp / (hp + EPSF));
            const float v = (4.0f / (PIF * PIF)) * da * da;
            const float alpha = v / (1.0f - iou + v + EPSF);
            float ci = iou - rho2 / c2 - alpha * v;
            ci = fminf(fmaxf(ci, -1.0f), 1.0f);
            box_p  = 1.0f - ci;
            objp_p = bce_fast(obj[cell], 1.0f);
        }
    }

    // Phase D: full-map negative objectness sum (no LDS dependency; float4)
    {
        const float4* obj4 = (const float4*)obj;
        const int n4 = HW >> 2;
        for (int i = tid; i < n4; i += NTH) {
            const float4 v = obj4[i];
            neg_p += bce0_fast(v.x) + bce0_fast(v.y) + bce0_fast(v.z) + bce0_fast(v.w);
        }
    }
    __syncthreads();

    // Phase B: subtract bce(obj,0) once per DISTINCT positive cell
    if (tid < NBOX && sh_mask[tid]) {
        const int cell = sh_cell[tid];
        bool first = true;
        for (int j = 0; j < tid; ++j)
            if (sh_mask[j] && sh_cell[j] == cell) { first = false; break; }
        if (first) sub_p = bce0_fast(obj[cell]);
    }

    // Phase C: class BCE, fully unrolled so all ~10 scattered loads are in
    // flight simultaneously (one ~900-cyc latency round instead of five)
    {
        float xs[10], tg[10];
        bool  act[10];
        #pragma unroll
        for (int k = 0; k < 10; ++k) {
            const int i = tid + k * NTH;
            act[k] = false;
            if (i < NBOX * NCLS) {
                const int n = i / NCLS;
                const int c = i - n * NCLS;
                if (sh_mask[n]) {
                    act[k] = true;
                    xs[k]  = cls[(size_t)c * HW + sh_cell[n]];
                    tg[k]  = (c == sh_lab[n]) ? 1.0f : 0.0f;
                }
            }
        }
        #pragma unroll
        for (int k = 0; k < 10; ++k)
            if (act[k]) cls_p += bce_fast(xs[k], tg[k]);
    }

    // Block reduction of 6 partials (shuffle within wave64, LDS across 8 waves)
    float vals[6] = { box_p, objp_p, cls_p, neg_p, sub_p, npos_p };
    const int wave = tid >> 6, lane = tid & 63;
    #pragma unroll
    for (int k = 0; k < 6; ++k) {
        const float v = wave_reduce(vals[k]);
        if (lane == 0) red[k * 8 + wave] = v;
    }
    __syncthreads();
    if (tid == 0) {
        float t[6];
        #pragma unroll
        for (int k = 0; k < 6; ++k) {
            float acc = 0.0f;
            #pragma unroll
            for (int w = 0; w < 8; ++w) acc += red[k * 8 + w];
            t[k] = acc;
        }
        const bool has_pos = t[5] > 0.0f;
        const float obj_l = has_pos ? (t[1] + (t[3] - t[4]) * 0.05f)
                                    : (t[3] / (float)HW) * 0.1f;
        part[bid * 4 + 0] = has_pos ? t[0] : 0.0f;
        part[bid * 4 + 1] = obj_l;
        part[bid * 4 + 2] = has_pos ? t[2] : 0.0f;
        part[bid * 4 + 3] = t[5];
    }
}

// Reduce the 192 per-block partials and emit [loss, box_loss, obj_loss, cls_loss]
__global__ __launch_bounds__(256) void detloss_final(
    const float* __restrict__ part, float* __restrict__ out)
{
    const int tid = threadIdx.x;
    float vb = 0.0f, vo = 0.0f, vc = 0.0f, vn = 0.0f;
    if (tid < 3 * NB) {
        vb = part[tid * 4 + 0];
        vo = part[tid * 4 + 1];
        vc = part[tid * 4 + 2];
        vn = part[tid * 4 + 3];
    }
    __shared__ float red[4 * 4];
    float vals[4] = { vb, vo, vc, vn };
    const int wave = tid >> 6, lane = tid & 63;
    #pragma unroll
    for (int k = 0; k < 4; ++k) {
        const float v = wave_reduce(vals[k]);
        if (lane == 0) red[k * 4 + wave] = v;
    }
    __syncthreads();
    if (tid == 0) {
        float t[4];
        #pragma unroll
        for (int k = 0; k < 4; ++k)
            t[k] = red[k * 4 + 0] + red[k * 4 + 1] + red[k * 4 + 2] + red[k * 4 + 3];
        const float norm = fmaxf(t[3], 1.0f);
        const float box_loss = t[0] / norm;
        const float cls_loss = t[2] / norm;
        const float obj_loss = t[1] / (float)(NB * 3);
        const float loss = 7.5f * box_loss + 1.0f * obj_loss + 0.5f * cls_loss;
        out[0] = loss;
        out[1] = box_loss;
        out[2] = obj_loss;
        out[3] = cls_loss;
    }
}

extern "C" void kernel_launch(void* const* d_in, const int* in_sizes, int n_in,
                              void* d_out, int out_size, void* d_ws, size_t ws_size,
                              hipStream_t stream) {
    const float* p3b = (const float*)d_in[0];
    const float* p3o = (const float*)d_in[1];
    const float* p3c = (const float*)d_in[2];
    const float* p4b = (const float*)d_in[3];
    const float* p4o = (const float*)d_in[4];
    const float* p4c = (const float*)d_in[5];
    const float* p5b = (const float*)d_in[6];
    const float* p5o = (const float*)d_in[7];
    const float* p5c = (const float*)d_in[8];
    const float* boxes = (const float*)d_in[9];
    const int*   labels = (const int*)d_in[10];

    float* part = (float*)d_ws;       // 192 * 4 floats, fully written before read
    float* out  = (float*)d_out;

    detloss_main<<<dim3(3 * NB), dim3(NTH), 0, stream>>>(
        p3b, p3o, p3c, p4b, p4o, p4c, p5b, p5o, p5c, boxes, labels, part);
    detloss_final<<<dim3(1), dim3(256), 0, stream>>>(part, out);
}